// Round 1
// baseline (1032.525 us; speedup 1.0000x reference)
//
#include <hip/hip_runtime.h>
#include <stdint.h>

#define N_TOK 8192
#define EMB 1024
#define HID 4096
#define NEXP 8

// ---- types ----
typedef _Float16 f16x8 __attribute__((ext_vector_type(8)));
typedef _Float16 f16x4 __attribute__((ext_vector_type(4)));
typedef short    s16x8 __attribute__((ext_vector_type(8)));
typedef float    f32x4 __attribute__((ext_vector_type(4)));

typedef __attribute__((address_space(1))) const void gvoid_t;
typedef __attribute__((address_space(3))) void lvoid_t;

__device__ __forceinline__ void async16(const void* g, void* l) {
  __builtin_amdgcn_global_load_lds((gvoid_t*)g, (lvoid_t*)l, 16, 0, 0);
}

__device__ __forceinline__ unsigned short f2bf(float f) {
  unsigned u = __builtin_bit_cast(unsigned, f);
  u += 0x7fffu + ((u >> 16) & 1u);   // RTNE (no NaN in this data)
  return (unsigned short)(u >> 16);
}

// ---- cast x -> bf16 (FFN A operand) + fp16 hi/lo split (router A operand) ----
__global__ __launch_bounds__(256) void k_cast_x(const float* __restrict__ x,
    unsigned short* __restrict__ xb, _Float16* __restrict__ xhi, _Float16* __restrict__ xlo) {
  int i = (blockIdx.x * 256 + threadIdx.x) << 2;
  float4 v = *(const float4*)(x + i);
  ushort4 b;
  b.x = f2bf(v.x); b.y = f2bf(v.y); b.z = f2bf(v.z); b.w = f2bf(v.w);
  *(ushort4*)(xb + i) = b;
  float vv[4] = {v.x, v.y, v.z, v.w};
  f16x4 hi, lo;
#pragma unroll
  for (int j = 0; j < 4; j++) {
    _Float16 h = (_Float16)vv[j];
    hi[j] = h;
    lo[j] = (_Float16)(vv[j] - (float)h);
  }
  *(f16x4*)(xhi + i) = hi;
  *(f16x4*)(xlo + i) = lo;
}

// ---- transpose+cast Wr1 [k][n] -> [n][k] fp16 hi/lo, scaled by 256 (argmax-invariant) ----
__global__ __launch_bounds__(256) void k_trans_wr1(const float* __restrict__ src,
    _Float16* __restrict__ dhi, _Float16* __restrict__ dlo) {
  int nblk = blockIdx.x >> 4, kc = blockIdx.x & 15;
  int n = (nblk << 8) + threadIdx.x;
  int k0 = kc << 6;
  for (int k = k0; k < k0 + 64; k += 8) {
    f16x8 hi, lo;
#pragma unroll
    for (int j = 0; j < 8; j++) {
      float w = src[(size_t)(k + j) * EMB + n] * 256.0f;
      _Float16 h = (_Float16)w;
      hi[j] = h;
      lo[j] = (_Float16)(w - (float)h);
    }
    *(f16x8*)(dhi + (size_t)n * EMB + k) = hi;
    *(f16x8*)(dlo + (size_t)n * EMB + k) = lo;
  }
}

// ---- transpose+cast expert weights [e][K][Nn] fp32 -> [e][Nn][K] bf16 ----
__global__ __launch_bounds__(256) void k_transcast_bf16(const float* __restrict__ src,
    unsigned short* __restrict__ dst, int K, int Nn, int nb, int kcCount) {
  int b = blockIdx.x;
  int e = b / (nb * kcCount);
  int r = b % (nb * kcCount);
  int nblk = r / kcCount, kc = r % kcCount;
  int n = (nblk << 8) + threadIdx.x;
  const float* s = src + (size_t)e * K * Nn;
  unsigned short* d = dst + (size_t)e * K * Nn + (size_t)n * K;
  int k0 = kc << 7;
  for (int k = k0; k < k0 + 128; k += 8) {
    ushort4 o0, o1;
    o0.x = f2bf(s[(size_t)(k + 0) * Nn + n]);
    o0.y = f2bf(s[(size_t)(k + 1) * Nn + n]);
    o0.z = f2bf(s[(size_t)(k + 2) * Nn + n]);
    o0.w = f2bf(s[(size_t)(k + 3) * Nn + n]);
    o1.x = f2bf(s[(size_t)(k + 4) * Nn + n]);
    o1.y = f2bf(s[(size_t)(k + 5) * Nn + n]);
    o1.z = f2bf(s[(size_t)(k + 6) * Nn + n]);
    o1.w = f2bf(s[(size_t)(k + 7) * Nn + n]);
    *(ushort4*)(d + k) = o0;
    *(ushort4*)(d + k + 4) = o1;
  }
}

// ---- router GEMM: h_s = relu(256*(x@Wr1+br1)) via fp16 2-way split, fp32-accurate ----
__global__ __launch_bounds__(256) void k_router_gemm(
    const _Float16* __restrict__ Ah, const _Float16* __restrict__ Al,
    const _Float16* __restrict__ Bh, const _Float16* __restrict__ Bl,
    const float* __restrict__ br1, float* __restrict__ hOut) {
  __shared__ __align__(16) _Float16 sAh[4096], sAl[4096], sBh[4096], sBl[4096];
  const int tid = threadIdx.x, lane = tid & 63, wave = tid >> 6;
  const int m0 = (blockIdx.x >> 3) << 7;
  const int n0 = (blockIdx.x & 7) << 7;
  const int srow = (wave << 5) + (lane >> 2);
  const int scol = (lane & 3) << 3;
  const size_t aBase = (size_t)(m0 + srow) * EMB + scol;
  const size_t bBase = (size_t)(n0 + srow) * EMB + scol;
  _Float16* lAh = sAh + (wave << 10);
  _Float16* lAl = sAl + (wave << 10);
  _Float16* lBh = sBh + (wave << 10);
  _Float16* lBl = sBl + (wave << 10);
  const int q = lane >> 4, c = lane & 15;
  const int msub = (wave & 1) << 6, nsub = (wave >> 1) << 6;
  f32x4 acc[4][4];
#pragma unroll
  for (int i = 0; i < 4; i++)
#pragma unroll
    for (int j = 0; j < 4; j++) acc[i][j] = (f32x4){0.f, 0.f, 0.f, 0.f};

  for (int kk = 0; kk < EMB; kk += 32) {
    async16(Ah + aBase + kk, lAh);
    async16(Ah + aBase + 16 * EMB + kk, lAh + 512);
    async16(Al + aBase + kk, lAl);
    async16(Al + aBase + 16 * EMB + kk, lAl + 512);
    async16(Bh + bBase + kk, lBh);
    async16(Bh + bBase + 16 * EMB + kk, lBh + 512);
    async16(Bl + bBase + kk, lBl);
    async16(Bl + bBase + 16 * EMB + kk, lBl + 512);
    __syncthreads();
    f16x8 fah[4], fal[4], fbh[4], fbl[4];
#pragma unroll
    for (int i = 0; i < 4; i++) {
      int ar = msub + (i << 4) + c;
      int br = nsub + (i << 4) + c;
      fah[i] = *(const f16x8*)(sAh + (ar << 5) + (q << 3));
      fal[i] = *(const f16x8*)(sAl + (ar << 5) + (q << 3));
      fbh[i] = *(const f16x8*)(sBh + (br << 5) + (q << 3));
      fbl[i] = *(const f16x8*)(sBl + (br << 5) + (q << 3));
    }
#pragma unroll
    for (int mi = 0; mi < 4; mi++)
#pragma unroll
      for (int ni = 0; ni < 4; ni++) {
        acc[mi][ni] = __builtin_amdgcn_mfma_f32_16x16x32_f16(fah[mi], fbh[ni], acc[mi][ni], 0, 0, 0);
        acc[mi][ni] = __builtin_amdgcn_mfma_f32_16x16x32_f16(fah[mi], fbl[ni], acc[mi][ni], 0, 0, 0);
        acc[mi][ni] = __builtin_amdgcn_mfma_f32_16x16x32_f16(fal[mi], fbh[ni], acc[mi][ni], 0, 0, 0);
      }
    __syncthreads();
  }
#pragma unroll
  for (int mi = 0; mi < 4; mi++)
#pragma unroll
    for (int ni = 0; ni < 4; ni++) {
      int gn = n0 + nsub + (ni << 4) + c;
      float bias = 256.0f * br1[gn];
#pragma unroll
      for (int i2 = 0; i2 < 4; i2++) {
        int gm = m0 + msub + (mi << 4) + (q << 2) + i2;
        float v = acc[mi][ni][i2] + bias;
        hOut[(size_t)gm * EMB + gn] = v > 0.f ? v : 0.f;
      }
    }
}

// ---- logits + argmax (first-max tie-break, matches np.argmax) ----
__global__ __launch_bounds__(256) void k_logits(const float* __restrict__ h,
    const float* __restrict__ Wr2, const float* __restrict__ br2, int* __restrict__ chosen) {
  __shared__ __align__(16) float sW[EMB * NEXP];
  int tid = threadIdx.x;
  for (int i = tid; i < EMB * NEXP; i += 256) sW[i] = Wr2[i];
  __syncthreads();
  int lane = tid & 63, wave = tid >> 6;
  int t = blockIdx.x * 4 + wave;
  const float* hr = h + (size_t)t * EMB;
  float acc[8] = {0.f, 0.f, 0.f, 0.f, 0.f, 0.f, 0.f, 0.f};
#pragma unroll
  for (int i = 0; i < 16; i++) {
    int k = (i << 6) + lane;
    float v = hr[k];
    float4 w0 = *(const float4*)(sW + (k << 3));
    float4 w1 = *(const float4*)(sW + (k << 3) + 4);
    acc[0] += v * w0.x; acc[1] += v * w0.y; acc[2] += v * w0.z; acc[3] += v * w0.w;
    acc[4] += v * w1.x; acc[5] += v * w1.y; acc[6] += v * w1.z; acc[7] += v * w1.w;
  }
#pragma unroll
  for (int off = 32; off > 0; off >>= 1)
#pragma unroll
    for (int e = 0; e < 8; e++) acc[e] += __shfl_down(acc[e], off);
  if (lane == 0) {
    float best = acc[0] + 256.0f * br2[0];
    int bi = 0;
#pragma unroll
    for (int e = 1; e < 8; e++) {
      float l = acc[e] + 256.0f * br2[e];
      if (l > best) { best = l; bi = e; }
    }
    chosen[t] = bi;
  }
}

// ---- tiny routing-bookkeeping kernels ----
// meta: [0..7] counts, [8..15] cursors, [16..24] offsets, [25] T,
//       [32..103] sched_e, [112..183] sched_m0, [192..263] sched_end
__global__ void k_zero(int* meta) { meta[threadIdx.x] = 0; }

__global__ __launch_bounds__(256) void k_hist(const int* __restrict__ chosen, int* meta) {
  int i = blockIdx.x * 256 + threadIdx.x;
  atomicAdd(&meta[chosen[i]], 1);
}

__global__ void k_sched(int* meta) {
  int off = 0;
  for (int e = 0; e < 8; e++) { meta[16 + e] = off; off += meta[e]; }
  meta[24] = off;
  int t = 0;
  for (int e = 0; e < 8; e++) {
    int beg = meta[16 + e], end = meta[16 + e + 1];
    for (int m = beg; m < end; m += 128) {
      meta[32 + t] = e;
      meta[112 + t] = m;
      meta[192 + t] = (m + 128 < end) ? (m + 128) : end;
      t++;
    }
  }
  meta[25] = t;
}

__global__ __launch_bounds__(256) void k_scatter(const int* __restrict__ chosen,
                                                 int* meta, int* __restrict__ perm) {
  int i = blockIdx.x * 256 + threadIdx.x;
  int e = chosen[i];
  int pos = meta[16 + e] + atomicAdd(&meta[8 + e], 1);
  perm[pos] = i;
}

// ---- FFN layer 1 (grouped, gathered-A, bf16 MFMA): hidden = relu(x[perm]@W1[e]+b1[e]) ----
__global__ __launch_bounds__(256) void k_ffn1(
    const unsigned short* __restrict__ xb, const unsigned short* __restrict__ w1t,
    const float* __restrict__ b1, const int* __restrict__ perm,
    const int* __restrict__ meta, unsigned short* __restrict__ hidden) {
  const int mt = blockIdx.x >> 5;
  if (mt >= meta[25]) return;
  const int nt = blockIdx.x & 31;
  const int e = meta[32 + mt];
  const int row0 = meta[112 + mt];
  const int rend = meta[192 + mt];
  const int n0 = nt << 7;
  __shared__ __align__(16) unsigned short sA[4096], sB[4096];
  const int tid = threadIdx.x, lane = tid & 63, wave = tid >> 6;
  const int srow = (wave << 5) + (lane >> 2);
  const int scol = (lane & 3) << 3;
  int ra0 = row0 + srow, ra1 = row0 + srow + 16;
  if (ra0 > rend - 1) ra0 = rend - 1;
  if (ra1 > rend - 1) ra1 = rend - 1;
  const int t0 = perm[ra0], t1 = perm[ra1];
  const unsigned short* a0 = xb + (size_t)t0 * EMB + scol;
  const unsigned short* a1 = xb + (size_t)t1 * EMB + scol;
  const unsigned short* bsrc = w1t + (size_t)e * EMB * HID + (size_t)(n0 + srow) * EMB + scol;
  unsigned short* lA = sA + (wave << 10);
  unsigned short* lB = sB + (wave << 10);
  const int q = lane >> 4, c = lane & 15;
  const int msub = (wave & 1) << 6, nsub = (wave >> 1) << 6;
  f32x4 acc[4][4];
#pragma unroll
  for (int i = 0; i < 4; i++)
#pragma unroll
    for (int j = 0; j < 4; j++) acc[i][j] = (f32x4){0.f, 0.f, 0.f, 0.f};

  for (int kk = 0; kk < EMB; kk += 32) {
    async16(a0 + kk, lA);
    async16(a1 + kk, lA + 512);
    async16(bsrc + kk, lB);
    async16(bsrc + 16 * EMB + kk, lB + 512);
    __syncthreads();
    s16x8 fa[4], fb[4];
#pragma unroll
    for (int i = 0; i < 4; i++) {
      fa[i] = *(const s16x8*)(sA + ((msub + (i << 4) + c) << 5) + (q << 3));
      fb[i] = *(const s16x8*)(sB + ((nsub + (i << 4) + c) << 5) + (q << 3));
    }
#pragma unroll
    for (int mi = 0; mi < 4; mi++)
#pragma unroll
      for (int ni = 0; ni < 4; ni++)
        acc[mi][ni] = __builtin_amdgcn_mfma_f32_16x16x32_bf16(fa[mi], fb[ni], acc[mi][ni], 0, 0, 0);
    __syncthreads();
  }
#pragma unroll
  for (int mi = 0; mi < 4; mi++)
#pragma unroll
    for (int ni = 0; ni < 4; ni++) {
      int gn = n0 + nsub + (ni << 4) + c;
      float bias = b1[e * HID + gn];
#pragma unroll
      for (int i2 = 0; i2 < 4; i2++) {
        int rs = row0 + msub + (mi << 4) + (q << 2) + i2;
        if (rs < rend) {
          float v = acc[mi][ni][i2] + bias;
          v = v > 0.f ? v : 0.f;
          hidden[(size_t)rs * HID + gn] = f2bf(v);
        }
      }
    }
}

// ---- FFN layer 2 (grouped, bf16 MFMA, scatter epilogue): out[perm] = hidden@W2[e]+b2[e] ----
__global__ __launch_bounds__(256) void k_ffn2(
    const unsigned short* __restrict__ hidden, const unsigned short* __restrict__ w2t,
    const float* __restrict__ b2, const int* __restrict__ perm,
    const int* __restrict__ meta, float* __restrict__ out) {
  const int mt = blockIdx.x >> 3;
  if (mt >= meta[25]) return;
  const int nt = blockIdx.x & 7;
  const int e = meta[32 + mt];
  const int row0 = meta[112 + mt];
  const int rend = meta[192 + mt];
  const int n0 = nt << 7;
  __shared__ __align__(16) unsigned short sA[4096], sB[4096];
  const int tid = threadIdx.x, lane = tid & 63, wave = tid >> 6;
  const int srow = (wave << 5) + (lane >> 2);
  const int scol = (lane & 3) << 3;
  int ra0 = row0 + srow, ra1 = row0 + srow + 16;
  if (ra0 > N_TOK - 1) ra0 = N_TOK - 1;
  if (ra1 > N_TOK - 1) ra1 = N_TOK - 1;
  const unsigned short* a0 = hidden + (size_t)ra0 * HID + scol;
  const unsigned short* a1 = hidden + (size_t)ra1 * HID + scol;
  const unsigned short* bsrc = w2t + (size_t)e * HID * EMB + (size_t)(n0 + srow) * HID + scol;
  unsigned short* lA = sA + (wave << 10);
  unsigned short* lB = sB + (wave << 10);
  const int q = lane >> 4, c = lane & 15;
  const int msub = (wave & 1) << 6, nsub = (wave >> 1) << 6;
  f32x4 acc[4][4];
#pragma unroll
  for (int i = 0; i < 4; i++)
#pragma unroll
    for (int j = 0; j < 4; j++) acc[i][j] = (f32x4){0.f, 0.f, 0.f, 0.f};

  for (int kk = 0; kk < HID; kk += 32) {
    async16(a0 + kk, lA);
    async16(a1 + kk, lA + 512);
    async16(bsrc + kk, lB);
    async16(bsrc + 16 * HID + kk, lB + 512);
    __syncthreads();
    s16x8 fa[4], fb[4];
#pragma unroll
    for (int i = 0; i < 4; i++) {
      fa[i] = *(const s16x8*)(sA + ((msub + (i << 4) + c) << 5) + (q << 3));
      fb[i] = *(const s16x8*)(sB + ((nsub + (i << 4) + c) << 5) + (q << 3));
    }
#pragma unroll
    for (int mi = 0; mi < 4; mi++)
#pragma unroll
      for (int ni = 0; ni < 4; ni++)
        acc[mi][ni] = __builtin_amdgcn_mfma_f32_16x16x32_bf16(fa[mi], fb[ni], acc[mi][ni], 0, 0, 0);
    __syncthreads();
  }
#pragma unroll
  for (int mi = 0; mi < 4; mi++)
#pragma unroll
    for (int ni = 0; ni < 4; ni++) {
      int gn = n0 + nsub + (ni << 4) + c;
      float bias = b2[e * EMB + gn];
#pragma unroll
      for (int i2 = 0; i2 < 4; i2++) {
        int rs = row0 + msub + (mi << 4) + (q << 2) + i2;
        if (rs < rend) {
          int orig = perm[rs];
          out[(size_t)orig * EMB + gn] = acc[mi][ni][i2] + bias;
        }
      }
    }
}

// ---- launch ----
// Workspace layout (bytes). REQUIRES ws_size >= 289,476,608 (~276 MiB).
extern "C" void kernel_launch(void* const* d_in, const int* in_sizes, int n_in,
                              void* d_out, int out_size, void* d_ws, size_t ws_size,
                              hipStream_t stream) {
  const float* x   = (const float*)d_in[0];
  const float* Wr1 = (const float*)d_in[1];
  const float* br1 = (const float*)d_in[2];
  const float* Wr2 = (const float*)d_in[3];
  const float* br2 = (const float*)d_in[4];
  const float* W1  = (const float*)d_in[5];
  const float* b1  = (const float*)d_in[6];
  const float* W2  = (const float*)d_in[7];
  const float* b2  = (const float*)d_in[8];
  float* out = (float*)d_out;
  char* ws = (char*)d_ws;

  unsigned short* w1t    = (unsigned short*)(ws + 0);          // 67,108,864
  unsigned short* w2t    = (unsigned short*)(ws + 67108864);   // 67,108,864
  unsigned short* xb     = (unsigned short*)(ws + 134217728);  // 16,777,216
  _Float16*       xhi    = (_Float16*)(ws + 150994944);        // 16,777,216
  _Float16*       xlo    = (_Float16*)(ws + 167772160);        // 16,777,216
  _Float16*       whi    = (_Float16*)(ws + 184549376);        //  2,097,152
  _Float16*       wlo    = (_Float16*)(ws + 186646528);        //  2,097,152
  float*          hbuf   = (float*)(ws + 188743680);           // 33,554,432
  unsigned short* hidden = (unsigned short*)(ws + 222298112);  // 67,108,864
  int*            chosen = (int*)(ws + 289406976);             //     32,768
  int*            perm   = (int*)(ws + 289439744);             //     32,768
  int*            meta   = (int*)(ws + 289472512);             //      4,096

  k_cast_x<<<dim3(8192), dim3(256), 0, stream>>>(x, xb, xhi, xlo);
  k_trans_wr1<<<dim3(64), dim3(256), 0, stream>>>(Wr1, whi, wlo);
  k_transcast_bf16<<<dim3(1024), dim3(256), 0, stream>>>(W1, w1t, 1024, 4096, 16, 8);
  k_transcast_bf16<<<dim3(1024), dim3(256), 0, stream>>>(W2, w2t, 4096, 1024, 4, 32);
  k_router_gemm<<<dim3(512), dim3(256), 0, stream>>>(xhi, xlo, whi, wlo, br1, hbuf);
  k_logits<<<dim3(2048), dim3(256), 0, stream>>>(hbuf, Wr2, br2, chosen);
  k_zero<<<dim3(1), dim3(256), 0, stream>>>(meta);
  k_hist<<<dim3(32), dim3(256), 0, stream>>>(chosen, meta);
  k_sched<<<dim3(1), dim3(1), 0, stream>>>(meta);
  k_scatter<<<dim3(32), dim3(256), 0, stream>>>(chosen, meta, perm);
  k_ffn1<<<dim3(2304), dim3(256), 0, stream>>>(xb, w1t, b1, perm, meta, hidden);
  k_ffn2<<<dim3(576), dim3(256), 0, stream>>>(hidden, w2t, b2, perm, meta, out);
}

// Round 2
// 775.671 us; speedup vs baseline: 1.3311x; 1.3311x over previous
//
#include <hip/hip_runtime.h>
#include <stdint.h>

#define N_TOK 8192
#define EMB 1024
#define HID 4096
#define NEXP 8

// ---- types ----
typedef _Float16 f16x8 __attribute__((ext_vector_type(8)));
typedef _Float16 f16x4 __attribute__((ext_vector_type(4)));
typedef short    s16x8 __attribute__((ext_vector_type(8)));
typedef unsigned short u16x8 __attribute__((ext_vector_type(8)));
typedef float    f32x4 __attribute__((ext_vector_type(4)));

typedef __attribute__((address_space(1))) const void gvoid_t;
typedef __attribute__((address_space(3))) void lvoid_t;

__device__ __forceinline__ void async16(const void* g, void* l) {
  __builtin_amdgcn_global_load_lds((gvoid_t*)g, (lvoid_t*)l, 16, 0, 0);
}

__device__ __forceinline__ unsigned short f2bf(float f) {
  unsigned u = __builtin_bit_cast(unsigned, f);
  u += 0x7fffu + ((u >> 16) & 1u);   // RTNE (no NaN in this data)
  return (unsigned short)(u >> 16);
}

// ---- cast x -> bf16 (FFN A operand) + fp16 hi/lo split (router A operand) ----
__global__ __launch_bounds__(256) void k_cast_x(const float* __restrict__ x,
    unsigned short* __restrict__ xb, _Float16* __restrict__ xhi, _Float16* __restrict__ xlo) {
  int i = (blockIdx.x * 256 + threadIdx.x) << 2;
  float4 v = *(const float4*)(x + i);
  ushort4 b;
  b.x = f2bf(v.x); b.y = f2bf(v.y); b.z = f2bf(v.z); b.w = f2bf(v.w);
  *(ushort4*)(xb + i) = b;
  float vv[4] = {v.x, v.y, v.z, v.w};
  f16x4 hi, lo;
#pragma unroll
  for (int j = 0; j < 4; j++) {
    _Float16 h = (_Float16)vv[j];
    hi[j] = h;
    lo[j] = (_Float16)(vv[j] - (float)h);
  }
  *(f16x4*)(xhi + i) = hi;
  *(f16x4*)(xlo + i) = lo;
}

// ---- transpose+cast Wr1 [k][n] -> [n][k] fp16 hi/lo, scaled by 256 (argmax-invariant) ----
__global__ __launch_bounds__(256) void k_trans_wr1(const float* __restrict__ src,
    _Float16* __restrict__ dhi, _Float16* __restrict__ dlo) {
  int nblk = blockIdx.x >> 4, kc = blockIdx.x & 15;
  int n = (nblk << 8) + threadIdx.x;
  int k0 = kc << 6;
  for (int k = k0; k < k0 + 64; k += 8) {
    f16x8 hi, lo;
#pragma unroll
    for (int j = 0; j < 8; j++) {
      float w = src[(size_t)(k + j) * EMB + n] * 256.0f;
      _Float16 h = (_Float16)w;
      hi[j] = h;
      lo[j] = (_Float16)(w - (float)h);
    }
    *(f16x8*)(dhi + (size_t)n * EMB + k) = hi;
    *(f16x8*)(dlo + (size_t)n * EMB + k) = lo;
  }
}

// ---- LDS-tiled transpose+cast expert weights [e][K][Nn] fp32 -> [e][Nn][K] bf16 ----
// Tile: 64 (k) x 256 (n). Reads: 4B fully coalesced along n. Writes: 8 lanes per
// output row -> 8 x 128B fully-covered contiguous segments per wave-instruction.
__global__ __launch_bounds__(256) void k_transcast_v2(const float* __restrict__ src,
    unsigned short* __restrict__ dst, int K, int Nn, int ktiles, int ntiles) {
  __shared__ __align__(16) unsigned short lds[256 * 72];  // 36,864 B, row stride 72
  int b = blockIdx.x;
  int e = b / (ktiles * ntiles);
  int r = b % (ktiles * ntiles);
  int kt = r / ntiles, nt = r % ntiles;
  int k0 = kt << 6, n0 = nt << 8;
  const float* s = src + (size_t)e * K * Nn;
  unsigned short* d = dst + (size_t)e * K * Nn;
  int tid = threadIdx.x;
  const float* scol = s + n0 + tid;
#pragma unroll 4
  for (int k = 0; k < 64; k += 2) {
    float a  = scol[(size_t)(k0 + k) * Nn];
    float bv = scol[(size_t)(k0 + k + 1) * Nn];
    unsigned p = (unsigned)f2bf(a) | ((unsigned)f2bf(bv) << 16);
    *(unsigned*)(lds + tid * 72 + k) = p;
  }
  __syncthreads();
  int c = tid & 7, nl = tid >> 3;
#pragma unroll
  for (int p2 = 0; p2 < 8; p2++) {
    int n = (p2 << 5) + nl;
    u16x8 v = *(const u16x8*)(lds + n * 72 + (c << 3));
    *(u16x8*)(d + (size_t)(n0 + n) * K + k0 + (c << 3)) = v;
  }
}

// ---- router GEMM: h_s = relu(256*(x@Wr1+br1)) via fp16 2-way split, fp32-accurate ----
__global__ __launch_bounds__(256) void k_router_gemm(
    const _Float16* __restrict__ Ah, const _Float16* __restrict__ Al,
    const _Float16* __restrict__ Bh, const _Float16* __restrict__ Bl,
    const float* __restrict__ br1, float* __restrict__ hOut) {
  __shared__ __align__(16) _Float16 sAh[4096], sAl[4096], sBh[4096], sBl[4096];
  const int tid = threadIdx.x, lane = tid & 63, wave = tid >> 6;
  const int m0 = (blockIdx.x >> 3) << 7;
  const int n0 = (blockIdx.x & 7) << 7;
  const int srow = (wave << 5) + (lane >> 2);
  const int scol = (lane & 3) << 3;
  const size_t aBase = (size_t)(m0 + srow) * EMB + scol;
  const size_t bBase = (size_t)(n0 + srow) * EMB + scol;
  _Float16* lAh = sAh + (wave << 10);
  _Float16* lAl = sAl + (wave << 10);
  _Float16* lBh = sBh + (wave << 10);
  _Float16* lBl = sBl + (wave << 10);
  const int q = lane >> 4, c = lane & 15;
  const int msub = (wave & 1) << 6, nsub = (wave >> 1) << 6;
  f32x4 acc[4][4];
#pragma unroll
  for (int i = 0; i < 4; i++)
#pragma unroll
    for (int j = 0; j < 4; j++) acc[i][j] = (f32x4){0.f, 0.f, 0.f, 0.f};

  for (int kk = 0; kk < EMB; kk += 32) {
    async16(Ah + aBase + kk, lAh);
    async16(Ah + aBase + 16 * EMB + kk, lAh + 512);
    async16(Al + aBase + kk, lAl);
    async16(Al + aBase + 16 * EMB + kk, lAl + 512);
    async16(Bh + bBase + kk, lBh);
    async16(Bh + bBase + 16 * EMB + kk, lBh + 512);
    async16(Bl + bBase + kk, lBl);
    async16(Bl + bBase + 16 * EMB + kk, lBl + 512);
    __syncthreads();
    f16x8 fah[4], fal[4], fbh[4], fbl[4];
#pragma unroll
    for (int i = 0; i < 4; i++) {
      int ar = msub + (i << 4) + c;
      int br = nsub + (i << 4) + c;
      fah[i] = *(const f16x8*)(sAh + (ar << 5) + (q << 3));
      fal[i] = *(const f16x8*)(sAl + (ar << 5) + (q << 3));
      fbh[i] = *(const f16x8*)(sBh + (br << 5) + (q << 3));
      fbl[i] = *(const f16x8*)(sBl + (br << 5) + (q << 3));
    }
#pragma unroll
    for (int mi = 0; mi < 4; mi++)
#pragma unroll
      for (int ni = 0; ni < 4; ni++) {
        acc[mi][ni] = __builtin_amdgcn_mfma_f32_16x16x32_f16(fah[mi], fbh[ni], acc[mi][ni], 0, 0, 0);
        acc[mi][ni] = __builtin_amdgcn_mfma_f32_16x16x32_f16(fah[mi], fbl[ni], acc[mi][ni], 0, 0, 0);
        acc[mi][ni] = __builtin_amdgcn_mfma_f32_16x16x32_f16(fal[mi], fbh[ni], acc[mi][ni], 0, 0, 0);
      }
    __syncthreads();
  }
#pragma unroll
  for (int mi = 0; mi < 4; mi++)
#pragma unroll
    for (int ni = 0; ni < 4; ni++) {
      int gn = n0 + nsub + (ni << 4) + c;
      float bias = 256.0f * br1[gn];
#pragma unroll
      for (int i2 = 0; i2 < 4; i2++) {
        int gm = m0 + msub + (mi << 4) + (q << 2) + i2;
        float v = acc[mi][ni][i2] + bias;
        hOut[(size_t)gm * EMB + gn] = v > 0.f ? v : 0.f;
      }
    }
}

// ---- logits + argmax (first-max tie-break, matches np.argmax) ----
__global__ __launch_bounds__(256) void k_logits(const float* __restrict__ h,
    const float* __restrict__ Wr2, const float* __restrict__ br2, int* __restrict__ chosen) {
  __shared__ __align__(16) float sW[EMB * NEXP];
  int tid = threadIdx.x;
  for (int i = tid; i < EMB * NEXP; i += 256) sW[i] = Wr2[i];
  __syncthreads();
  int lane = tid & 63, wave = tid >> 6;
  int t = blockIdx.x * 4 + wave;
  const float* hr = h + (size_t)t * EMB;
  float acc[8] = {0.f, 0.f, 0.f, 0.f, 0.f, 0.f, 0.f, 0.f};
#pragma unroll
  for (int i = 0; i < 16; i++) {
    int k = (i << 6) + lane;
    float v = hr[k];
    float4 w0 = *(const float4*)(sW + (k << 3));
    float4 w1 = *(const float4*)(sW + (k << 3) + 4);
    acc[0] += v * w0.x; acc[1] += v * w0.y; acc[2] += v * w0.z; acc[3] += v * w0.w;
    acc[4] += v * w1.x; acc[5] += v * w1.y; acc[6] += v * w1.z; acc[7] += v * w1.w;
  }
#pragma unroll
  for (int off = 32; off > 0; off >>= 1)
#pragma unroll
    for (int e = 0; e < 8; e++) acc[e] += __shfl_down(acc[e], off);
  if (lane == 0) {
    float best = acc[0] + 256.0f * br2[0];
    int bi = 0;
#pragma unroll
    for (int e = 1; e < 8; e++) {
      float l = acc[e] + 256.0f * br2[e];
      if (l > best) { best = l; bi = e; }
    }
    chosen[t] = bi;
  }
}

// ---- tiny routing-bookkeeping kernels ----
// meta: [0..7] counts, [8..15] cursors, [16..24] offsets, [25] T,
//       [32..103] sched_e, [112..183] sched_m0, [192..263] sched_end
__global__ void k_zero(int* meta) { meta[threadIdx.x] = 0; }

__global__ __launch_bounds__(256) void k_hist(const int* __restrict__ chosen, int* meta) {
  int i = blockIdx.x * 256 + threadIdx.x;
  atomicAdd(&meta[chosen[i]], 1);
}

// Parallel schedule build: every thread redundantly computes 8-elem prefix sums,
// thread i fills schedule slot i (T <= 71 < 128).
__global__ __launch_bounds__(128) void k_sched(int* meta) {
  __shared__ int cnt[8];
  int tid = threadIdx.x;
  if (tid < 8) cnt[tid] = meta[tid];
  __syncthreads();
  int off[9]; off[0] = 0;
#pragma unroll
  for (int e = 0; e < 8; e++) off[e + 1] = off[e] + cnt[e];
  int ts[9]; ts[0] = 0;
#pragma unroll
  for (int e = 0; e < 8; e++) ts[e + 1] = ts[e] + ((cnt[e] + 127) >> 7);
  int T = ts[8];
  if (tid < 8) meta[16 + tid] = off[tid];
  if (tid == 0) { meta[24] = off[8]; meta[25] = T; }
  if (tid < T) {
    int e = 0;
    while (ts[e + 1] <= tid) e++;
    int m = off[e] + ((tid - ts[e]) << 7);
    int end = off[e + 1];
    meta[32 + tid] = e;
    meta[112 + tid] = m;
    meta[192 + tid] = (m + 128 < end) ? m + 128 : end;
  }
}

__global__ __launch_bounds__(256) void k_scatter(const int* __restrict__ chosen,
                                                 int* meta, int* __restrict__ perm) {
  int i = blockIdx.x * 256 + threadIdx.x;
  int e = chosen[i];
  int pos = meta[16 + e] + atomicAdd(&meta[8 + e], 1);
  perm[pos] = i;
}

// ---- FFN layer 1 (grouped, gathered-A, bf16 MFMA): hidden = relu(x[perm]@W1[e]+b1[e]) ----
__global__ __launch_bounds__(256) void k_ffn1(
    const unsigned short* __restrict__ xb, const unsigned short* __restrict__ w1t,
    const float* __restrict__ b1, const int* __restrict__ perm,
    const int* __restrict__ meta, unsigned short* __restrict__ hidden) {
  const int mt = blockIdx.x >> 5;
  if (mt >= meta[25]) return;
  const int nt = blockIdx.x & 31;
  const int e = meta[32 + mt];
  const int row0 = meta[112 + mt];
  const int rend = meta[192 + mt];
  const int n0 = nt << 7;
  __shared__ __align__(16) unsigned short sA[4096], sB[4096];
  const int tid = threadIdx.x, lane = tid & 63, wave = tid >> 6;
  const int srow = (wave << 5) + (lane >> 2);
  const int scol = (lane & 3) << 3;
  int ra0 = row0 + srow, ra1 = row0 + srow + 16;
  if (ra0 > rend - 1) ra0 = rend - 1;
  if (ra1 > rend - 1) ra1 = rend - 1;
  const int t0 = perm[ra0], t1 = perm[ra1];
  const unsigned short* a0 = xb + (size_t)t0 * EMB + scol;
  const unsigned short* a1 = xb + (size_t)t1 * EMB + scol;
  const unsigned short* bsrc = w1t + (size_t)e * EMB * HID + (size_t)(n0 + srow) * EMB + scol;
  unsigned short* lA = sA + (wave << 10);
  unsigned short* lB = sB + (wave << 10);
  const int q = lane >> 4, c = lane & 15;
  const int msub = (wave & 1) << 6, nsub = (wave >> 1) << 6;
  f32x4 acc[4][4];
#pragma unroll
  for (int i = 0; i < 4; i++)
#pragma unroll
    for (int j = 0; j < 4; j++) acc[i][j] = (f32x4){0.f, 0.f, 0.f, 0.f};

  for (int kk = 0; kk < EMB; kk += 32) {
    async16(a0 + kk, lA);
    async16(a1 + kk, lA + 512);
    async16(bsrc + kk, lB);
    async16(bsrc + 16 * EMB + kk, lB + 512);
    __syncthreads();
    s16x8 fa[4], fb[4];
#pragma unroll
    for (int i = 0; i < 4; i++) {
      fa[i] = *(const s16x8*)(sA + ((msub + (i << 4) + c) << 5) + (q << 3));
      fb[i] = *(const s16x8*)(sB + ((nsub + (i << 4) + c) << 5) + (q << 3));
    }
#pragma unroll
    for (int mi = 0; mi < 4; mi++)
#pragma unroll
      for (int ni = 0; ni < 4; ni++)
        acc[mi][ni] = __builtin_amdgcn_mfma_f32_16x16x32_bf16(fa[mi], fb[ni], acc[mi][ni], 0, 0, 0);
    __syncthreads();
  }
#pragma unroll
  for (int mi = 0; mi < 4; mi++)
#pragma unroll
    for (int ni = 0; ni < 4; ni++) {
      int gn = n0 + nsub + (ni << 4) + c;
      float bias = b1[e * HID + gn];
#pragma unroll
      for (int i2 = 0; i2 < 4; i2++) {
        int rs = row0 + msub + (mi << 4) + (q << 2) + i2;
        if (rs < rend) {
          float v = acc[mi][ni][i2] + bias;
          v = v > 0.f ? v : 0.f;
          hidden[(size_t)rs * HID + gn] = f2bf(v);
        }
      }
    }
}

// ---- FFN layer 2 (grouped, bf16 MFMA, scatter epilogue): out[perm] = hidden@W2[e]+b2[e] ----
__global__ __launch_bounds__(256) void k_ffn2(
    const unsigned short* __restrict__ hidden, const unsigned short* __restrict__ w2t,
    const float* __restrict__ b2, const int* __restrict__ perm,
    const int* __restrict__ meta, float* __restrict__ out) {
  const int mt = blockIdx.x >> 3;
  if (mt >= meta[25]) return;
  const int nt = blockIdx.x & 7;
  const int e = meta[32 + mt];
  const int row0 = meta[112 + mt];
  const int rend = meta[192 + mt];
  const int n0 = nt << 7;
  __shared__ __align__(16) unsigned short sA[4096], sB[4096];
  const int tid = threadIdx.x, lane = tid & 63, wave = tid >> 6;
  const int srow = (wave << 5) + (lane >> 2);
  const int scol = (lane & 3) << 3;
  int ra0 = row0 + srow, ra1 = row0 + srow + 16;
  if (ra0 > N_TOK - 1) ra0 = N_TOK - 1;
  if (ra1 > N_TOK - 1) ra1 = N_TOK - 1;
  const unsigned short* a0 = hidden + (size_t)ra0 * HID + scol;
  const unsigned short* a1 = hidden + (size_t)ra1 * HID + scol;
  const unsigned short* bsrc = w2t + (size_t)e * HID * EMB + (size_t)(n0 + srow) * HID + scol;
  unsigned short* lA = sA + (wave << 10);
  unsigned short* lB = sB + (wave << 10);
  const int q = lane >> 4, c = lane & 15;
  const int msub = (wave & 1) << 6, nsub = (wave >> 1) << 6;
  f32x4 acc[4][4];
#pragma unroll
  for (int i = 0; i < 4; i++)
#pragma unroll
    for (int j = 0; j < 4; j++) acc[i][j] = (f32x4){0.f, 0.f, 0.f, 0.f};

  for (int kk = 0; kk < HID; kk += 32) {
    async16(a0 + kk, lA);
    async16(a1 + kk, lA + 512);
    async16(bsrc + kk, lB);
    async16(bsrc + 16 * HID + kk, lB + 512);
    __syncthreads();
    s16x8 fa[4], fb[4];
#pragma unroll
    for (int i = 0; i < 4; i++) {
      fa[i] = *(const s16x8*)(sA + ((msub + (i << 4) + c) << 5) + (q << 3));
      fb[i] = *(const s16x8*)(sB + ((nsub + (i << 4) + c) << 5) + (q << 3));
    }
#pragma unroll
    for (int mi = 0; mi < 4; mi++)
#pragma unroll
      for (int ni = 0; ni < 4; ni++)
        acc[mi][ni] = __builtin_amdgcn_mfma_f32_16x16x32_bf16(fa[mi], fb[ni], acc[mi][ni], 0, 0, 0);
    __syncthreads();
  }
#pragma unroll
  for (int mi = 0; mi < 4; mi++)
#pragma unroll
    for (int ni = 0; ni < 4; ni++) {
      int gn = n0 + nsub + (ni << 4) + c;
      float bias = b2[e * EMB + gn];
#pragma unroll
      for (int i2 = 0; i2 < 4; i2++) {
        int rs = row0 + msub + (mi << 4) + (q << 2) + i2;
        if (rs < rend) {
          int orig = perm[rs];
          out[(size_t)orig * EMB + gn] = acc[mi][ni][i2] + bias;
        }
      }
    }
}

// ---- launch ----
// Workspace layout (bytes). REQUIRES ws_size >= 289,476,608 (~276 MiB).
extern "C" void kernel_launch(void* const* d_in, const int* in_sizes, int n_in,
                              void* d_out, int out_size, void* d_ws, size_t ws_size,
                              hipStream_t stream) {
  const float* x   = (const float*)d_in[0];
  const float* Wr1 = (const float*)d_in[1];
  const float* br1 = (const float*)d_in[2];
  const float* Wr2 = (const float*)d_in[3];
  const float* br2 = (const float*)d_in[4];
  const float* W1  = (const float*)d_in[5];
  const float* b1  = (const float*)d_in[6];
  const float* W2  = (const float*)d_in[7];
  const float* b2  = (const float*)d_in[8];
  float* out = (float*)d_out;
  char* ws = (char*)d_ws;

  unsigned short* w1t    = (unsigned short*)(ws + 0);          // 67,108,864
  unsigned short* w2t    = (unsigned short*)(ws + 67108864);   // 67,108,864
  unsigned short* xb     = (unsigned short*)(ws + 134217728);  // 16,777,216
  _Float16*       xhi    = (_Float16*)(ws + 150994944);        // 16,777,216
  _Float16*       xlo    = (_Float16*)(ws + 167772160);        // 16,777,216
  _Float16*       whi    = (_Float16*)(ws + 184549376);        //  2,097,152
  _Float16*       wlo    = (_Float16*)(ws + 186646528);        //  2,097,152
  float*          hbuf   = (float*)(ws + 188743680);           // 33,554,432
  unsigned short* hidden = (unsigned short*)(ws + 222298112);  // 67,108,864
  int*            chosen = (int*)(ws + 289406976);             //     32,768
  int*            perm   = (int*)(ws + 289439744);             //     32,768
  int*            meta   = (int*)(ws + 289472512);             //      4,096

  k_cast_x<<<dim3(8192), dim3(256), 0, stream>>>(x, xb, xhi, xlo);
  k_trans_wr1<<<dim3(64), dim3(256), 0, stream>>>(Wr1, whi, wlo);
  // W1: K=1024 (EMB), Nn=4096 (HID): ktiles=16, ntiles=16 -> 8*256=2048 blocks
  k_transcast_v2<<<dim3(2048), dim3(256), 0, stream>>>(W1, w1t, 1024, 4096, 16, 16);
  // W2: K=4096 (HID), Nn=1024 (EMB): ktiles=64, ntiles=4 -> 8*256=2048 blocks
  k_transcast_v2<<<dim3(2048), dim3(256), 0, stream>>>(W2, w2t, 4096, 1024, 64, 4);
  k_router_gemm<<<dim3(512), dim3(256), 0, stream>>>(xhi, xlo, whi, wlo, br1, hbuf);
  k_logits<<<dim3(2048), dim3(256), 0, stream>>>(hbuf, Wr2, br2, chosen);
  k_zero<<<dim3(1), dim3(256), 0, stream>>>(meta);
  k_hist<<<dim3(32), dim3(256), 0, stream>>>(chosen, meta);
  k_sched<<<dim3(1), dim3(128), 0, stream>>>(meta);
  k_scatter<<<dim3(32), dim3(256), 0, stream>>>(chosen, meta, perm);
  k_ffn1<<<dim3(2304), dim3(256), 0, stream>>>(xb, w1t, b1, perm, meta, hidden);
  k_ffn2<<<dim3(576), dim3(256), 0, stream>>>(hidden, w2t, b2, perm, meta, out);
}